// Round 14
// baseline (210.018 us; speedup 1.0000x reference)
//
#include <hip/hip_runtime.h>

// Problem constants (from reference)
#define N_PTS 8388608
#define FX 758.03967f
#define CXC 621.46572f
#define FY 761.62359f
#define CYC 756.86402f
#define U_MAX 1231.0f   // WIDTH - 1
#define W_MAX 1615.0f   // HEIGHT - 1
#define MIN_D 1.0f
#define MAX_D_R 10.0f
#define MAX_D_M 5.0f

#define THREADS 256
#define BLOCKS (N_PTS / 1024)    // 1024 points per block -> 8192 blocks
#define ZBLOCKS 2048             // zerofill: 2048 x 256 x 12 float4 = 100.7 MB

typedef float nfloat4 __attribute__((ext_vector_type(4)));

// Workspace layout (uints): [16 + b] (b in [0,BLOCKS)) = per-block partial
// count, PLAIN STORE (no atomics, no zero-init needed).
//
// Evidence ledger (frustum dur / hbm_bytes / eff BW):
//  R5 strided x3:  62.0/152/2.45   R6 LDS-coalesced: 58.5/151/2.59
//  R7 strided x6:  86.8/209/2.41   R8 R6+nt st:      59.6/151/2.54
//  R9 depth x2:    60.3/151/2.51   R10 persistent:   77.5/203/2.62
//  R11 fused pose/slots: 60.5/151/2.49
//  R12 +NT LOADS:  total 196.7->186.9 (-10us REAL). 2.5 pin = L2 read/write
//      contention; read-once points no longer allocates in L2.
//  R13 +nt stores: 186.4 (neutral, within noise). Cache-policy 2x2 complete.
//  => mixed read+write stream runs ~3.0 TB/s; the harness's own fill kernel
//     proves pure-write streams run 6.8 TB/s. Output is ~97% zeros (narrow
//     frustum on 5*N(0,1) points).
//  THIS ROUND: split the write work -- kernel 1 zero-fills out as a pure
//  write stream (plain cached stores: leaves zero lines in L2/L3 so sparse
//  RMW hits cache); kernel 2 = R12 staged-nt-load front end + SPARSE stores
//  (masked rows only, ~3%). Bit-exact: memset-zero == +0.0f == current zeros;
//  masked rows computed identically.
//  R4: fused finalize w/ __threadfence+ticket serialized everything (571us).
//  R3: nt on 48B-strided stores amplified WRITE 1.74x.

__global__ __launch_bounds__(256) void zero_kernel(float4* __restrict__ out) {
    const int t = threadIdx.x;
    const long base = (long)blockIdx.x * 3072;   // 12 float4 per thread
    float4 z = make_float4(0.0f, 0.0f, 0.0f, 0.0f);
    #pragma unroll
    for (int k = 0; k < 12; ++k)
        out[base + t + k * 256] = z;             // coalesced 1KB wave bursts
}

__global__ __launch_bounds__(256) void frustum_kernel(const float4* __restrict__ pts,
                                                      const float* __restrict__ x,
                                                      const float* __restrict__ y,
                                                      const float* __restrict__ z,
                                                      const float* __restrict__ roll,
                                                      const float* __restrict__ pitch,
                                                      const float* __restrict__ yaw,
                                                      float* __restrict__ ws,
                                                      float* __restrict__ outf) {
    // 256 threads x 4 points = 1024 points = 768 float4 = 12 KB per block.
    __shared__ float4 st[768];
    __shared__ float S[12];

    const int t = threadIdx.x;
    const long gbase = (long)blockIdx.x * 768;   // block's first float4 index

    // Coalesced stage-in, NONTEMPORAL loads (R12-verified win).
    const nfloat4* npts = (const nfloat4*)pts;
    nfloat4 a0 = __builtin_nontemporal_load(&npts[gbase + t]);
    nfloat4 a1 = __builtin_nontemporal_load(&npts[gbase + t + 256]);
    nfloat4 a2 = __builtin_nontemporal_load(&npts[gbase + t + 512]);
    st[t]       = *(const float4*)&a0;
    st[t + 256] = *(const float4*)&a1;
    st[t + 512] = *(const float4*)&a2;

    // Per-block pose setup (bit-identical expressions; R10-R13 verified).
    if (t == 0) {
        float cr = cosf(*roll), sr = sinf(*roll);
        float cp = cosf(*pitch), sp = sinf(*pitch);
        float cy = cosf(*yaw),  sy = sinf(*yaw);
        // R = Rx(roll) @ Ry(pitch) @ Rz(yaw), row-major. At the zero pose this
        // is exactly identity (with signed zeros), so v = points bit-exact.
        S[0] = cp * cy;                S[1] = -(cp * sy);             S[2] = sp;
        S[3] = cr * sy + sr * sp * cy; S[4] = cr * cy - sr * sp * sy; S[5] = -(sr * cp);
        S[6] = sr * sy - cr * sp * cy; S[7] = sr * cy + cr * sp * sy; S[8] = cr * cp;
        S[9] = *x; S[10] = *y; S[11] = *z;
    }
    __syncthreads();

    const float R0 = S[0], R1 = S[1], R2 = S[2];
    const float R3 = S[3], R4 = S[4], R5 = S[5];
    const float R6 = S[6], R7 = S[7], R8 = S[8];
    const float t0 = S[9], t1 = S[10], t2 = S[11];

    // Thread t owns floats [12t, 12t+12) of the block = points [4t, 4t+4).
    const float4* pv = (const float4*)((const float*)st + t * 12);
    float4 q0 = pv[0];
    float4 q1 = pv[1];
    float4 q2 = pv[2];

    // Global float index of this thread's first output element.
    const long obase = (long)blockIdx.x * 3072 + (long)t * 12;

    int cnt = 0;
    auto proc = [&](float px, float py, float pz, long ofs) {
        float d0 = px - t0, d1 = py - t1, d2 = pz - t2;
        // ascending-k fma accumulation to match the numpy reference's matmul
        float v0 = fmaf(d2, R6, fmaf(d1, R3, d0 * R0));
        float v1 = fmaf(d2, R7, fmaf(d1, R4, d0 * R1));
        float v2 = fmaf(d2, R8, fmaf(d1, R5, d0 * R2));
        float p0 = fmaf(v2, CXC, v0 * FX);
        float p1 = fmaf(v2, CYC, v1 * FY);
        float u = p0 / v2;           // IEEE div; inf/nan on v2==0 compares false, same as numpy mask
        float w = p1 / v2;
        bool fov = (v2 > 0.0f) && (u > 1.0f) && (u < U_MAX) && (w > 1.0f) && (w < W_MAX);
        if (fov && (v2 > MIN_D) && (v2 < MAX_D_R)) cnt++;
        bool m = fov && (v2 > MIN_D) && (v2 < MAX_D_M);
        // SPARSE: only masked rows are written; zero_kernel provided the rest.
        if (m) {
            outf[ofs + 0] = v0;
            outf[ofs + 1] = v1;
            outf[ofs + 2] = v2;
        }
    };

    proc(q0.x, q0.y, q0.z, obase + 0);   // point 0
    proc(q0.w, q1.x, q1.y, obase + 3);   // point 1
    proc(q1.z, q1.w, q2.x, obase + 6);   // point 2
    proc(q2.y, q2.z, q2.w, obase + 9);   // point 3

    // wave reduce (wave = 64), block reduce in LDS, ONE PLAIN STORE per block
    // into its own slot (no atomics; ws poisoned each call so write always).
    for (int off = 32; off > 0; off >>= 1) cnt += __shfl_down(cnt, off, 64);
    __shared__ int red[4];
    const int wave = threadIdx.x >> 6;
    if ((threadIdx.x & 63) == 0) red[wave] = cnt;
    __syncthreads();
    if (threadIdx.x == 0) {
        ((unsigned int*)ws)[16 + blockIdx.x] =
            (unsigned int)(red[0] + red[1] + red[2] + red[3]);
    }
}

__global__ void finalize_kernel(const float* __restrict__ ws, float* __restrict__ out) {
    const unsigned int* slots = (const unsigned int*)ws + 16;
    unsigned int c = 0;
    for (int i = threadIdx.x; i < BLOCKS; i += 256) c += slots[i];
    for (int off = 32; off > 0; off >>= 1) c += __shfl_down(c, off, 64);
    __shared__ unsigned int red[4];
    const int wave = threadIdx.x >> 6;
    if ((threadIdx.x & 63) == 0) red[wave] = c;
    __syncthreads();
    if (threadIdx.x == 0) {
        unsigned int tot = red[0] + red[1] + red[2] + red[3];
        out[(long)3 * N_PTS] = 1.0f / ((float)tot + 1e-6f);
    }
}

extern "C" void kernel_launch(void* const* d_in, const int* in_sizes, int n_in,
                              void* d_out, int out_size, void* d_ws, size_t ws_size,
                              hipStream_t stream) {
    const float* points = (const float*)d_in[0];
    const float* x      = (const float*)d_in[1];
    const float* y      = (const float*)d_in[2];
    const float* z      = (const float*)d_in[3];
    const float* roll   = (const float*)d_in[4];
    const float* pitch  = (const float*)d_in[5];
    const float* yaw    = (const float*)d_in[6];
    float* ws = (float*)d_ws;
    float* out = (float*)d_out;

    zero_kernel<<<ZBLOCKS, THREADS, 0, stream>>>((float4*)out);
    frustum_kernel<<<BLOCKS, THREADS, 0, stream>>>((const float4*)points,
                                                   x, y, z, roll, pitch, yaw,
                                                   ws, out);
    finalize_kernel<<<1, 256, 0, stream>>>(ws, out);
}

// Round 15
// 207.223 us; speedup vs baseline: 1.0135x; 1.0135x over previous
//
#include <hip/hip_runtime.h>

// Problem constants (from reference)
#define N_PTS 8388608
#define FX 758.03967f
#define CXC 621.46572f
#define FY 761.62359f
#define CYC 756.86402f
#define U_MAX 1231.0f   // WIDTH - 1
#define W_MAX 1615.0f   // HEIGHT - 1
#define MIN_D 1.0f
#define MAX_D_R 10.0f
#define MAX_D_M 5.0f

#define THREADS 256
#define BLOCKS (N_PTS / 1024)    // 1024 points per block -> 8192 blocks

typedef float nfloat4 __attribute__((ext_vector_type(4)));

// Workspace layout (uints): [16 + b] (b in [0,BLOCKS)) = per-block partial
// count, PLAIN STORE (no atomics, no zero-init needed).
//
// Evidence ledger (frustum dur / hbm_bytes / eff BW):
//  R5-R11: six structural levers null/negative; all variants 2.4-2.6 TB/s.
//  R12 +NT LOADS:  total 196.7->186.9 (-10us REAL). The 2.5 TB/s pin was L2
//      read/write contention; read-once points no longer allocates in L2.
//  R13 +nt stores: 186.4 (neutral). Cache-policy 2x2 complete. frustum ~50us.
//  R14 split (zero_kernel + sparse frustum): total 210 BUT the in-profile
//      control (poison fills, constant workload) ran 74us/5.4TB/s vs
//      59us/6.8TB/s on R12/R13 -- machine ~25% slower. (total - 2xfill) =
//      ~47us for zero+frustum vs R13's ~50 frustum-only => split likely fine,
//      needs a clean re-measure. THIS ROUND: same split, zeroing via
//      hipMemsetAsync (the 6.8TB/s fillBufferAligned path, graph-capture-safe;
//      all-zero bytes == +0.0f bit pattern, bit-exact).
//  R4: fused finalize w/ __threadfence+ticket serialized everything (571us).
//  R3: nt on 48B-strided stores amplified WRITE 1.74x.

__global__ __launch_bounds__(256) void frustum_kernel(const float4* __restrict__ pts,
                                                      const float* __restrict__ x,
                                                      const float* __restrict__ y,
                                                      const float* __restrict__ z,
                                                      const float* __restrict__ roll,
                                                      const float* __restrict__ pitch,
                                                      const float* __restrict__ yaw,
                                                      float* __restrict__ ws,
                                                      float* __restrict__ outf) {
    // 256 threads x 4 points = 1024 points = 768 float4 = 12 KB per block.
    __shared__ float4 st[768];
    __shared__ float S[12];

    const int t = threadIdx.x;
    const long gbase = (long)blockIdx.x * 768;   // block's first float4 index

    // Coalesced stage-in, NONTEMPORAL loads (R12-verified win).
    const nfloat4* npts = (const nfloat4*)pts;
    nfloat4 a0 = __builtin_nontemporal_load(&npts[gbase + t]);
    nfloat4 a1 = __builtin_nontemporal_load(&npts[gbase + t + 256]);
    nfloat4 a2 = __builtin_nontemporal_load(&npts[gbase + t + 512]);
    st[t]       = *(const float4*)&a0;
    st[t + 256] = *(const float4*)&a1;
    st[t + 512] = *(const float4*)&a2;

    // Per-block pose setup (bit-identical expressions; R10-R14 verified).
    if (t == 0) {
        float cr = cosf(*roll), sr = sinf(*roll);
        float cp = cosf(*pitch), sp = sinf(*pitch);
        float cy = cosf(*yaw),  sy = sinf(*yaw);
        // R = Rx(roll) @ Ry(pitch) @ Rz(yaw), row-major. At the zero pose this
        // is exactly identity (with signed zeros), so v = points bit-exact.
        S[0] = cp * cy;                S[1] = -(cp * sy);             S[2] = sp;
        S[3] = cr * sy + sr * sp * cy; S[4] = cr * cy - sr * sp * sy; S[5] = -(sr * cp);
        S[6] = sr * sy - cr * sp * cy; S[7] = sr * cy + cr * sp * sy; S[8] = cr * cp;
        S[9] = *x; S[10] = *y; S[11] = *z;
    }
    __syncthreads();

    const float R0 = S[0], R1 = S[1], R2 = S[2];
    const float R3 = S[3], R4 = S[4], R5 = S[5];
    const float R6 = S[6], R7 = S[7], R8 = S[8];
    const float t0 = S[9], t1 = S[10], t2 = S[11];

    // Thread t owns floats [12t, 12t+12) of the block = points [4t, 4t+4).
    const float4* pv = (const float4*)((const float*)st + t * 12);
    float4 q0 = pv[0];
    float4 q1 = pv[1];
    float4 q2 = pv[2];

    // Global float index of this thread's first output element.
    const long obase = (long)blockIdx.x * 3072 + (long)t * 12;

    int cnt = 0;
    auto proc = [&](float px, float py, float pz, long ofs) {
        float d0 = px - t0, d1 = py - t1, d2 = pz - t2;
        // ascending-k fma accumulation to match the numpy reference's matmul
        float v0 = fmaf(d2, R6, fmaf(d1, R3, d0 * R0));
        float v1 = fmaf(d2, R7, fmaf(d1, R4, d0 * R1));
        float v2 = fmaf(d2, R8, fmaf(d1, R5, d0 * R2));
        float p0 = fmaf(v2, CXC, v0 * FX);
        float p1 = fmaf(v2, CYC, v1 * FY);
        float u = p0 / v2;           // IEEE div; inf/nan on v2==0 compares false, same as numpy mask
        float w = p1 / v2;
        bool fov = (v2 > 0.0f) && (u > 1.0f) && (u < U_MAX) && (w > 1.0f) && (w < W_MAX);
        if (fov && (v2 > MIN_D) && (v2 < MAX_D_R)) cnt++;
        bool m = fov && (v2 > MIN_D) && (v2 < MAX_D_M);
        // SPARSE: only masked rows (~3%) are written; memset provided zeros.
        if (m) {
            outf[ofs + 0] = v0;
            outf[ofs + 1] = v1;
            outf[ofs + 2] = v2;
        }
    };

    proc(q0.x, q0.y, q0.z, obase + 0);   // point 0
    proc(q0.w, q1.x, q1.y, obase + 3);   // point 1
    proc(q1.z, q1.w, q2.x, obase + 6);   // point 2
    proc(q2.y, q2.z, q2.w, obase + 9);   // point 3

    // wave reduce (wave = 64), block reduce in LDS, ONE PLAIN STORE per block
    // into its own slot (no atomics; ws poisoned each call so write always).
    for (int off = 32; off > 0; off >>= 1) cnt += __shfl_down(cnt, off, 64);
    __shared__ int red[4];
    const int wave = threadIdx.x >> 6;
    if ((threadIdx.x & 63) == 0) red[wave] = cnt;
    __syncthreads();
    if (threadIdx.x == 0) {
        ((unsigned int*)ws)[16 + blockIdx.x] =
            (unsigned int)(red[0] + red[1] + red[2] + red[3]);
    }
}

__global__ void finalize_kernel(const float* __restrict__ ws, float* __restrict__ out) {
    const unsigned int* slots = (const unsigned int*)ws + 16;
    unsigned int c = 0;
    for (int i = threadIdx.x; i < BLOCKS; i += 256) c += slots[i];
    for (int off = 32; off > 0; off >>= 1) c += __shfl_down(c, off, 64);
    __shared__ unsigned int red[4];
    const int wave = threadIdx.x >> 6;
    if ((threadIdx.x & 63) == 0) red[wave] = c;
    __syncthreads();
    if (threadIdx.x == 0) {
        unsigned int tot = red[0] + red[1] + red[2] + red[3];
        out[(long)3 * N_PTS] = 1.0f / ((float)tot + 1e-6f);
    }
}

extern "C" void kernel_launch(void* const* d_in, const int* in_sizes, int n_in,
                              void* d_out, int out_size, void* d_ws, size_t ws_size,
                              hipStream_t stream) {
    const float* points = (const float*)d_in[0];
    const float* x      = (const float*)d_in[1];
    const float* y      = (const float*)d_in[2];
    const float* z      = (const float*)d_in[3];
    const float* roll   = (const float*)d_in[4];
    const float* pitch  = (const float*)d_in[5];
    const float* yaw    = (const float*)d_in[6];
    float* ws = (float*)d_ws;
    float* out = (float*)d_out;

    // Zero the verts region (3*N_PTS floats = 100.66 MB) via the runtime's
    // fill path (measured 6.8 TB/s in-profile). Stream-ordered, capture-safe.
    hipMemsetAsync(out, 0, (size_t)3 * N_PTS * sizeof(float), stream);

    frustum_kernel<<<BLOCKS, THREADS, 0, stream>>>((const float4*)points,
                                                   x, y, z, roll, pitch, yaw,
                                                   ws, out);
    finalize_kernel<<<1, 256, 0, stream>>>(ws, out);
}

// Round 16
// 186.647 us; speedup vs baseline: 1.1252x; 1.1102x over previous
//
#include <hip/hip_runtime.h>

// Problem constants (from reference)
#define N_PTS 8388608
#define FX 758.03967f
#define CXC 621.46572f
#define FY 761.62359f
#define CYC 756.86402f
#define U_MAX 1231.0f   // WIDTH - 1
#define W_MAX 1615.0f   // HEIGHT - 1
#define MIN_D 1.0f
#define MAX_D_R 10.0f
#define MAX_D_M 5.0f

#define THREADS 256
#define BLOCKS (N_PTS / 1024)    // 1024 points per block -> 8192 blocks

typedef float nfloat4 __attribute__((ext_vector_type(4)));

// Workspace layout (uints): [16 + b] (b in [0,BLOCKS)) = per-block partial
// count, PLAIN STORE (no atomics, no zero-init needed).
//
// Evidence ledger:
//  R5-R11: six structural levers null/negative; all variants 2.4-2.6 TB/s.
//  R12 +NT LOADS: total 196.7->186.9 (-10us REAL). The 2.5 TB/s pin was L2
//      read/write contention; read-once points no longer allocates in L2.
//  R13 +nt stores: 186.4 (neutral vs R12). BEST TOTAL. frustum ~50us.
//  R14/R15 (memset+sparse split): totals 210/207; harness fills slowed
//      59->73us in BOTH split rounds, and R15 showed 14KB fills at 73us
//      (impossible from clock speed alone). Split ADDS ~27MB writes/iter
//      (100 memset + 26 sparse vs 99 dense) and its fill slowdown is
//      correlated with the split two-for-two -> endogenous suspicion;
//      total is the honest metric -> split abandoned, REVERT to R13.
//  R4: fused finalize w/ __threadfence+ticket serialized everything (571us).
//  R3: nt on 48B-strided stores amplified WRITE 1.74x.

__global__ __launch_bounds__(256) void frustum_kernel(const float4* __restrict__ pts,
                                                      const float* __restrict__ x,
                                                      const float* __restrict__ y,
                                                      const float* __restrict__ z,
                                                      const float* __restrict__ roll,
                                                      const float* __restrict__ pitch,
                                                      const float* __restrict__ yaw,
                                                      float* __restrict__ ws,
                                                      float4* __restrict__ out) {
    // 256 threads x 4 points = 1024 points = 768 float4 = 12 KB per block.
    __shared__ float4 st[768];
    __shared__ float S[12];

    const int t = threadIdx.x;
    const long gbase = (long)blockIdx.x * 768;   // block's first float4 index

    // Coalesced stage-in, NONTEMPORAL loads (R12-verified win): read-once
    // points skips L2 allocation -> no contention with the write stream.
    const nfloat4* npts = (const nfloat4*)pts;
    nfloat4 a0 = __builtin_nontemporal_load(&npts[gbase + t]);
    nfloat4 a1 = __builtin_nontemporal_load(&npts[gbase + t + 256]);
    nfloat4 a2 = __builtin_nontemporal_load(&npts[gbase + t + 512]);
    st[t]       = *(const float4*)&a0;
    st[t + 256] = *(const float4*)&a1;
    st[t + 512] = *(const float4*)&a2;

    // Per-block pose setup (bit-identical expressions; R10-R15 verified).
    if (t == 0) {
        float cr = cosf(*roll), sr = sinf(*roll);
        float cp = cosf(*pitch), sp = sinf(*pitch);
        float cy = cosf(*yaw),  sy = sinf(*yaw);
        // R = Rx(roll) @ Ry(pitch) @ Rz(yaw), row-major. At the zero pose this
        // is exactly identity (with signed zeros), so v = points bit-exact.
        S[0] = cp * cy;                S[1] = -(cp * sy);             S[2] = sp;
        S[3] = cr * sy + sr * sp * cy; S[4] = cr * cy - sr * sp * sy; S[5] = -(sr * cp);
        S[6] = sr * sy - cr * sp * cy; S[7] = sr * cy + cr * sp * sy; S[8] = cr * cp;
        S[9] = *x; S[10] = *y; S[11] = *z;
    }
    __syncthreads();

    const float R0 = S[0], R1 = S[1], R2 = S[2];
    const float R3 = S[3], R4 = S[4], R5 = S[5];
    const float R6 = S[6], R7 = S[7], R8 = S[8];
    const float t0 = S[9], t1 = S[10], t2 = S[11];

    // Thread t owns floats [12t, 12t+12) of the block = same mapping as R5/R6,
    // so cnt/out are bit-identical.
    const float4* pv = (const float4*)((const float*)st + t * 12);
    float4 q0 = pv[0];
    float4 q1 = pv[1];
    float4 q2 = pv[2];

    int cnt = 0;
    auto proc = [&](float px, float py, float pz, float& ox, float& oy, float& oz) {
        float d0 = px - t0, d1 = py - t1, d2 = pz - t2;
        // ascending-k fma accumulation to match the numpy reference's matmul
        float v0 = fmaf(d2, R6, fmaf(d1, R3, d0 * R0));
        float v1 = fmaf(d2, R7, fmaf(d1, R4, d0 * R1));
        float v2 = fmaf(d2, R8, fmaf(d1, R5, d0 * R2));
        float p0 = fmaf(v2, CXC, v0 * FX);
        float p1 = fmaf(v2, CYC, v1 * FY);
        float u = p0 / v2;           // IEEE div; inf/nan on v2==0 compares false, same as numpy mask
        float w = p1 / v2;
        bool fov = (v2 > 0.0f) && (u > 1.0f) && (u < U_MAX) && (w > 1.0f) && (w < W_MAX);
        if (fov && (v2 > MIN_D) && (v2 < MAX_D_R)) cnt++;
        bool m = fov && (v2 > MIN_D) && (v2 < MAX_D_M);
        ox = m ? v0 : 0.0f;
        oy = m ? v1 : 0.0f;
        oz = m ? v2 : 0.0f;
    };

    float4 o0, o1, o2;
    proc(q0.x, q0.y, q0.z, o0.x, o0.y, o0.z);   // point 0
    proc(q0.w, q1.x, q1.y, o0.w, o1.x, o1.y);   // point 1
    proc(q1.z, q1.w, q2.x, o1.z, o1.w, o2.x);   // point 2
    proc(q2.y, q2.z, q2.w, o2.y, o2.z, o2.w);   // point 3

    // In-place writeback of my own 48B region (no cross-thread hazard).
    float4* wv = (float4*)((float*)st + t * 12);
    wv[0] = o0;
    wv[1] = o1;
    wv[2] = o2;
    __syncthreads();

    // Coalesced stage-out, NONTEMPORAL: full-line 1KB bursts stream straight
    // to HBM. R8/R13 verified WRITE_SIZE stays clean (98.6MB) on these stores.
    float4 s0 = st[t];
    float4 s1 = st[t + 256];
    float4 s2 = st[t + 512];
    __builtin_nontemporal_store(*(const nfloat4*)&s0, (nfloat4*)&out[gbase + t]);
    __builtin_nontemporal_store(*(const nfloat4*)&s1, (nfloat4*)&out[gbase + t + 256]);
    __builtin_nontemporal_store(*(const nfloat4*)&s2, (nfloat4*)&out[gbase + t + 512]);

    // wave reduce (wave = 64), block reduce in LDS, ONE PLAIN STORE per block
    // into its own slot (no atomics; ws poisoned each call so write always).
    for (int off = 32; off > 0; off >>= 1) cnt += __shfl_down(cnt, off, 64);
    __shared__ int red[4];
    const int wave = threadIdx.x >> 6;
    if ((threadIdx.x & 63) == 0) red[wave] = cnt;
    __syncthreads();
    if (threadIdx.x == 0) {
        ((unsigned int*)ws)[16 + blockIdx.x] =
            (unsigned int)(red[0] + red[1] + red[2] + red[3]);
    }
}

__global__ void finalize_kernel(const float* __restrict__ ws, float* __restrict__ out) {
    const unsigned int* slots = (const unsigned int*)ws + 16;
    unsigned int c = 0;
    for (int i = threadIdx.x; i < BLOCKS; i += 256) c += slots[i];
    for (int off = 32; off > 0; off >>= 1) c += __shfl_down(c, off, 64);
    __shared__ unsigned int red[4];
    const int wave = threadIdx.x >> 6;
    if ((threadIdx.x & 63) == 0) red[wave] = c;
    __syncthreads();
    if (threadIdx.x == 0) {
        unsigned int tot = red[0] + red[1] + red[2] + red[3];
        out[(long)3 * N_PTS] = 1.0f / ((float)tot + 1e-6f);
    }
}

extern "C" void kernel_launch(void* const* d_in, const int* in_sizes, int n_in,
                              void* d_out, int out_size, void* d_ws, size_t ws_size,
                              hipStream_t stream) {
    const float* points = (const float*)d_in[0];
    const float* x      = (const float*)d_in[1];
    const float* y      = (const float*)d_in[2];
    const float* z      = (const float*)d_in[3];
    const float* roll   = (const float*)d_in[4];
    const float* pitch  = (const float*)d_in[5];
    const float* yaw    = (const float*)d_in[6];
    float* ws = (float*)d_ws;
    float* out = (float*)d_out;

    frustum_kernel<<<BLOCKS, THREADS, 0, stream>>>((const float4*)points,
                                                   x, y, z, roll, pitch, yaw,
                                                   ws, (float4*)out);
    finalize_kernel<<<1, 256, 0, stream>>>(ws, out);
}